// Round 5
// baseline (813.525 us; speedup 1.0000x reference)
//
#include <hip/hip_runtime.h>
#include <hip/hip_bf16.h>
#include <cmath>

// CapsNet forward. conv2 via split-bf16 MFMA (3-product split: ah*bh + al*bh
// + ah*bl; al*bl term ~2^-18 dropped), conv1 fused fp32 on VALU.
// LDS A-operand layout: c1[pos][ci] with XOR-swizzled 8-ci k-groups:
//   addr_shorts(pos, kg, i) = pos*32 + ((kg ^ (pos&3))<<3) + i
// -> phase-B ds_read_b128 has every bank at its bandwidth minimum (8 acc/bank).
// ws (bytes): whi 10,616,832 | wlo 10,616,832 | xcaps 9,437,184 = 30.7 MB

typedef float f32x4 __attribute__((ext_vector_type(4)));
typedef short s16x8 __attribute__((ext_vector_type(8)));

static __device__ __forceinline__ short f2bf(float x) {
  __hip_bfloat16 h = __float2bfloat16(x);
  return *reinterpret_cast<short*>(&h);
}
static __device__ __forceinline__ float bf2f(short s) {
  __hip_bfloat16 h;
  *reinterpret_cast<short*>(&h) = s;
  return __bfloat162float(h);
}

// ---------------- w2 split + transpose: whi/wlo[tap][co][ci] ----------------
__global__ __launch_bounds__(256) void prep_w2(const float* __restrict__ w2,
                                               short* __restrict__ whi,
                                               short* __restrict__ wlo) {
  const int co = blockIdx.x;
  const int ci = threadIdx.x;
  const float* src = w2 + ((size_t)co * 256 + ci) * 81;  // contiguous taps
  for (int tap = 0; tap < 81; ++tap) {
    const float x = src[tap];
    const short hi = f2bf(x);
    const short lo = f2bf(x - bf2f(hi));
    const size_t idx = ((size_t)tap * 256 + co) * 256 + ci;  // ci coalesced
    whi[idx] = hi;
    wlo[idx] = lo;
  }
}

// ---------------- conv1 + conv2 via MFMA ----------------
__global__ __launch_bounds__(256) void conv2_mfma(
    const float* __restrict__ data, const float* __restrict__ w1,
    const float* __restrict__ b1, const short* __restrict__ whi,
    const short* __restrict__ wlo, const float* __restrict__ b2,
    float* __restrict__ xcaps) {
  const int t = threadIdx.x;
  const int b = blockIdx.x >> 1;
  const int coh = blockIdx.x & 1;
  const int lane = t & 63;
  const int wv = t >> 6;  // wave 0..3

  __shared__ float simg[28 * 36];   // image rows padded to 36 floats
  __shared__ short c1hi[400 * 32];  // swizzled [pos][ci-chunk 32]
  __shared__ short c1lo[400 * 32];

  for (int i = t; i < 784; i += 256)
    simg[(i / 28) * 36 + (i % 28)] = data[b * 784 + i];

  const int r16 = lane & 15;  // A row (M) / B col (N) / D col
  const int kg = lane >> 4;   // k-group: k = kg*8 + i

  // A-fragment spatial bases for the 3 M-tiles (pad rows clamped to pos 35)
  int base0[3], cpar[3];
#pragma unroll
  for (int m = 0; m < 3; ++m) {
    int pos = m * 16 + r16;
    if (pos > 35) pos = 35;  // garbage rows discarded at store
    const int oy = pos / 6, ox = pos % 6;
    base0[m] = (oy * 40 + ox * 2) * 32;  // spatial elem * 32 shorts
    cpar[m] = (ox * 2) & 3;
  }
  // B-fragment offsets (tap slab is 256co x 256ci)
  int boff[2], con[2];
  float bias[2];
#pragma unroll
  for (int j = 0; j < 2; ++j) {
    const int co = coh * 128 + (wv * 2 + j) * 16 + r16;
    con[j] = co;
    boff[j] = co * 256 + kg * 8;
    bias[j] = b2[co];
  }

  const f32x4 vzero = {0.f, 0.f, 0.f, 0.f};
  f32x4 acc[3][2];
#pragma unroll
  for (int m = 0; m < 3; ++m)
#pragma unroll
    for (int j = 0; j < 2; ++j) acc[m][j] = vzero;

  for (int chunk = 0; chunk < 8; ++chunk) {
    __syncthreads();  // simg ready / prev phase B done with c1 buffers
    // ---- phase A: conv1 (k9 s1, bias, relu) 32 ch -> swizzled bf16 LDS ----
    for (int task = t; task < 640; task += 256) {
      const int ci = task & 31, y = task >> 5;  // y 0..19
      const int ch = chunk * 32 + ci;
      const float* wr = w1 + ch * 81;
      const float bz = b1[ch];
      float a20[20];
#pragma unroll
      for (int ox = 0; ox < 20; ++ox) a20[ox] = bz;
#pragma unroll
      for (int ky = 0; ky < 9; ++ky) {
        float rr[28];
#pragma unroll
        for (int q = 0; q < 7; ++q)
          *(float4*)&rr[q * 4] = *(const float4*)&simg[(y + ky) * 36 + q * 4];
#pragma unroll
        for (int kx = 0; kx < 9; ++kx) {
          const float w = wr[ky * 9 + kx];
#pragma unroll
          for (int ox = 0; ox < 20; ++ox) a20[ox] = fmaf(w, rr[ox + kx], a20[ox]);
        }
      }
      const int kgc = ci >> 3, il = ci & 7;
#pragma unroll
      for (int x = 0; x < 20; ++x) {
        const int pos = y * 20 + x;           // pos&3 == x&3
        const int sw = pos * 32 + (((kgc ^ (x & 3)) << 3) + il);
        const float v = fmaxf(a20[x], 0.f);
        const short hi = f2bf(v);
        c1hi[sw] = hi;
        c1lo[sw] = f2bf(v - bf2f(hi));
      }
    }
    __syncthreads();
    // ---- phase B: 81 taps, K=32, 3-product split MFMA ----
    for (int ky = 0; ky < 9; ++ky) {
#pragma unroll
      for (int kx = 0; kx < 9; ++kx) {
        const int rowoff = (ky * 20 + kx) * 32;
        s16x8 ah[3], al[3];
#pragma unroll
        for (int m = 0; m < 3; ++m) {
          const int ix = base0[m] + rowoff + ((kg ^ ((cpar[m] + kx) & 3)) << 3);
          ah[m] = *(const s16x8*)&c1hi[ix];  // one b128 each
          al[m] = *(const s16x8*)&c1lo[ix];
        }
        const size_t tbase = (size_t)(ky * 9 + kx) * 65536 + chunk * 32;
        s16x8 bh[2], bl[2];
#pragma unroll
        for (int j = 0; j < 2; ++j) {
          bh[j] = *(const s16x8*)&whi[tbase + boff[j]];
          bl[j] = *(const s16x8*)&wlo[tbase + boff[j]];
        }
#pragma unroll
        for (int m = 0; m < 3; ++m)
#pragma unroll
          for (int j = 0; j < 2; ++j)
            acc[m][j] = __builtin_amdgcn_mfma_f32_16x16x32_bf16(ah[m], bh[j], acc[m][j], 0, 0, 0);
#pragma unroll
        for (int m = 0; m < 3; ++m)
#pragma unroll
          for (int j = 0; j < 2; ++j)
            acc[m][j] = __builtin_amdgcn_mfma_f32_16x16x32_bf16(al[m], bh[j], acc[m][j], 0, 0, 0);
#pragma unroll
        for (int m = 0; m < 3; ++m)
#pragma unroll
          for (int j = 0; j < 2; ++j)
            acc[m][j] = __builtin_amdgcn_mfma_f32_16x16x32_bf16(ah[m], bl[j], acc[m][j], 0, 0, 0);
      }
    }
  }
  // ---- store: D col=lane&15, row=(lane>>4)*4+reg; xcaps[b][n][d] ----
#pragma unroll
  for (int m = 0; m < 3; ++m) {
#pragma unroll
    for (int jj = 0; jj < 4; ++jj) {
      const int pos = m * 16 + kg * 4 + jj;
      if (pos < 36) {
#pragma unroll
        for (int j = 0; j < 2; ++j) {
          const int co = con[j];
          const int n = (co & 31) * 36 + pos;
          xcaps[((size_t)b * 1152 + n) * 8 + (co >> 5)] = acc[m][j][jj] + bias[j];
        }
      }
    }
  }
}

// ---------------- fused u_hat + routing: block per (o,b) ----------------
__global__ __launch_bounds__(256) void routing_fused(const float* __restrict__ xcaps,
                                                     const float* __restrict__ W,
                                                     float* __restrict__ out) {
  const int o = blockIdx.x >> 8;
  const int b = blockIdx.x & 255;
  const int t = threadIdx.x;
  const int k = t & 15, ng = t >> 4;
  __shared__ float xs[1152 * 9];  // x[b] padded stride 8->9
  __shared__ double redA[256];
  __shared__ double redB[256];
  __shared__ float s_s[16];
  __shared__ float s_sv;
  __shared__ double s_f;

  {
    const float4* src = (const float4*)(xcaps + (size_t)b * 9216);
    for (int idx = t; idx < 2304; idx += 256) {
      float4 v = src[idx];
      const int n = idx >> 1, h = idx & 1;
      float* dst = &xs[n * 9 + h * 4];
      dst[0] = v.x; dst[1] = v.y; dst[2] = v.z; dst[3] = v.w;
    }
  }
  __syncthreads();

  const int n0 = ng * 72;
  float u[72];
  const float* wp = W + ((size_t)(n0 * 10 + o) * 16 + k) * 8;
#pragma unroll
  for (int i = 0; i < 72; ++i) {
    const float* wq = wp + (size_t)i * 1280;
    const float4 wa = *(const float4*)wq;
    const float4 wb = *(const float4*)(wq + 4);
    const float* xp = &xs[(n0 + i) * 9];
    float s = fmaf(wa.x, xp[0], 0.f);
    s = fmaf(wa.y, xp[1], s);
    s = fmaf(wa.z, xp[2], s);
    s = fmaf(wa.w, xp[3], s);
    s = fmaf(wb.x, xp[4], s);
    s = fmaf(wb.y, xp[5], s);
    s = fmaf(wb.z, xp[6], s);
    s = fmaf(wb.w, xp[7], s);
    u[i] = s;
  }

  // ---- pass 1: uniform c = 1/1152 ----
  double S = 0.0;
#pragma unroll
  for (int i = 0; i < 72; ++i) S += (double)u[i];
  redA[t] = S;
  __syncthreads();
  if (t < 16) {
    double tt = 0.0;
#pragma unroll
    for (int g = 0; g < 16; ++g) tt += redA[g * 16 + t];
    s_s[t] = (float)(tt * (double)(1.0f / 1152.0f));
  }
  __syncthreads();
  if (t == 0) {
    double sn = 0.0;
#pragma unroll
    for (int kk = 0; kk < 16; ++kk) sn += (double)s_s[kk] * (double)s_s[kk];
    const double f = sn / ((1.0 + sn) * sqrt(sn));
    double sv = 0.0;
#pragma unroll
    for (int kk = 0; kk < 16; ++kk) sv += (double)s_s[kk] * f;
    s_sv = (float)sv;
  }
  __syncthreads();
  const float sv1 = s_sv;

  // ---- pass 2: logits u*sv1 ----
  double E = 0.0, EU = 0.0;
#pragma unroll
  for (int i = 0; i < 72; ++i) {
    const float e = expf(u[i] * sv1);
    E += (double)e;
    EU += (double)e * (double)u[i];
  }
  redA[t] = E; redB[t] = EU;
  __syncthreads();
  if (t < 16) {
    double te = 0.0, tu = 0.0;
#pragma unroll
    for (int g = 0; g < 16; ++g) { te += redA[g * 16 + t]; tu += redB[g * 16 + t]; }
    s_s[t] = (float)(tu / te);
  }
  __syncthreads();
  if (t == 0) {
    double sn = 0.0;
#pragma unroll
    for (int kk = 0; kk < 16; ++kk) sn += (double)s_s[kk] * (double)s_s[kk];
    const double f = sn / ((1.0 + sn) * sqrt(sn));
    double sv = 0.0;
#pragma unroll
    for (int kk = 0; kk < 16; ++kk) sv += (double)s_s[kk] * f;
    s_sv = sv1 + (float)sv;
  }
  __syncthreads();
  const float sv12 = s_sv;

  // ---- pass 3 -> output ----
  E = 0.0; EU = 0.0;
#pragma unroll
  for (int i = 0; i < 72; ++i) {
    const float e = expf(u[i] * sv12);
    E += (double)e;
    EU += (double)e * (double)u[i];
  }
  redA[t] = E; redB[t] = EU;
  __syncthreads();
  if (t < 16) {
    double te = 0.0, tu = 0.0;
#pragma unroll
    for (int g = 0; g < 16; ++g) { te += redA[g * 16 + t]; tu += redB[g * 16 + t]; }
    s_s[t] = (float)(tu / te);
  }
  __syncthreads();
  if (t == 0) {
    double sn = 0.0;
#pragma unroll
    for (int kk = 0; kk < 16; ++kk) sn += (double)s_s[kk] * (double)s_s[kk];
    s_f = sn / ((1.0 + sn) * sqrt(sn));
  }
  __syncthreads();
  if (t < 16) out[b * 160 + o * 16 + t] = (float)((double)s_s[t] * s_f);
}

extern "C" void kernel_launch(void* const* d_in, const int* in_sizes, int n_in,
                              void* d_out, int out_size, void* d_ws, size_t ws_size,
                              hipStream_t stream) {
  const float* data = (const float*)d_in[0];
  const float* w1   = (const float*)d_in[1];
  const float* b1   = (const float*)d_in[2];
  const float* w2   = (const float*)d_in[3];
  const float* b2   = (const float*)d_in[4];
  const float* W    = (const float*)d_in[5];
  float* out = (float*)d_out;

  short* whi   = (short*)d_ws;            // 5,308,416 shorts
  short* wlo   = whi + 5308416;           // 5,308,416 shorts
  float* xcaps = (float*)(wlo + 5308416); // 2,359,296 floats

  prep_w2<<<256, 256, 0, stream>>>(w2, whi, wlo);
  conv2_mfma<<<512, 256, 0, stream>>>(data, w1, b1, whi, wlo, b2, xcaps);
  routing_fused<<<2560, 256, 0, stream>>>(xcaps, W, out);
}

// Round 6
// 808.048 us; speedup vs baseline: 1.0068x; 1.0068x over previous
//
#include <hip/hip_runtime.h>
#include <hip/hip_bf16.h>
#include <cmath>

// CapsNet forward. conv2 via split-bf16 MFMA (3-product: ah*bh + al*bh + ah*bl;
// al*bl ~2^-18 dropped), conv1 fused fp32 on VALU.
// LDS A-layout: c1[pos][40 shorts] (ci 0..31 + 8 pad). Row stride 80 B makes
// consecutive pos rows start at bank 20*pos mod 32 = period-8 permutation of
// all eight 16B slots -> ds_read_b128 conflict-free in every 8-lane group.
// ws (bytes): whi 10,616,832 | wlo 10,616,832 | xcaps 9,437,184 = 30.7 MB

typedef float f32x4 __attribute__((ext_vector_type(4)));
typedef short s16x8 __attribute__((ext_vector_type(8)));

static __device__ __forceinline__ short f2bf(float x) {
  __hip_bfloat16 h = __float2bfloat16(x);
  return *reinterpret_cast<short*>(&h);
}
static __device__ __forceinline__ float bf2f(short s) {
  __hip_bfloat16 h;
  *reinterpret_cast<short*>(&h) = s;
  return __bfloat162float(h);
}

// ---------------- w2 split + transpose: whi/wlo[tap][co][ci] ----------------
__global__ __launch_bounds__(256) void prep_w2(const float* __restrict__ w2,
                                               short* __restrict__ whi,
                                               short* __restrict__ wlo) {
  const int co = blockIdx.x;
  const int ci = threadIdx.x;
  const float* src = w2 + ((size_t)co * 256 + ci) * 81;  // contiguous taps
  for (int tap = 0; tap < 81; ++tap) {
    const float x = src[tap];
    const short hi = f2bf(x);
    const short lo = f2bf(x - bf2f(hi));
    const size_t idx = ((size_t)tap * 256 + co) * 256 + ci;  // ci coalesced
    whi[idx] = hi;
    wlo[idx] = lo;
  }
}

// ---------------- conv1 + conv2 via MFMA ----------------
__global__ __launch_bounds__(256) void conv2_mfma(
    const float* __restrict__ data, const float* __restrict__ w1,
    const float* __restrict__ b1, const short* __restrict__ whi,
    const short* __restrict__ wlo, const float* __restrict__ b2,
    float* __restrict__ xcaps) {
  const int t = threadIdx.x;
  const int b = blockIdx.x >> 1;
  const int coh = blockIdx.x & 1;
  const int lane = t & 63;
  const int wv = t >> 6;  // wave 0..3

  __shared__ float simg[28 * 36];   // image rows padded to 36 floats
  __shared__ short c1hi[400 * 40];  // [pos][ci 0..31, pad to 40]
  __shared__ short c1lo[400 * 40];

  for (int i = t; i < 784; i += 256)
    simg[(i / 28) * 36 + (i % 28)] = data[b * 784 + i];

  const int r16 = lane & 15;  // A row (M) / B col (N) / D col
  const int kg = lane >> 4;   // k-group: k = kg*8 + i

  // A-fragment spatial bases for the 3 M-tiles (pad rows clamped to pos 35)
  int base0[3];
#pragma unroll
  for (int m = 0; m < 3; ++m) {
    int pos = m * 16 + r16;
    if (pos > 35) pos = 35;  // duplicate rows: same-addr broadcast, discarded
    const int oy = pos / 6, ox = pos % 6;
    base0[m] = (oy * 40 + ox * 2) * 40 + kg * 8;  // shorts
  }
  // B-fragment offsets (tap slab is 256co x 256ci)
  int boff[2], con[2];
  float bias[2];
#pragma unroll
  for (int j = 0; j < 2; ++j) {
    const int co = coh * 128 + (wv * 2 + j) * 16 + r16;
    con[j] = co;
    boff[j] = co * 256 + kg * 8;
    bias[j] = b2[co];
  }

  const f32x4 vzero = {0.f, 0.f, 0.f, 0.f};
  f32x4 acc[3][2];
#pragma unroll
  for (int m = 0; m < 3; ++m)
#pragma unroll
    for (int j = 0; j < 2; ++j) acc[m][j] = vzero;

  for (int chunk = 0; chunk < 8; ++chunk) {
    __syncthreads();  // simg ready / prev phase B done with c1 buffers
    // ---- phase A: conv1 (k9 s1, bias, relu) 32 ch -> bf16 hi/lo LDS ----
    for (int task = t; task < 640; task += 256) {
      const int ci = task & 31, y = task >> 5;  // y 0..19
      const int ch = chunk * 32 + ci;
      const float* wr = w1 + ch * 81;
      const float bz = b1[ch];
      float a20[20];
#pragma unroll
      for (int ox = 0; ox < 20; ++ox) a20[ox] = bz;
#pragma unroll
      for (int ky = 0; ky < 9; ++ky) {
        float rr[28];
#pragma unroll
        for (int q = 0; q < 7; ++q)
          *(float4*)&rr[q * 4] = *(const float4*)&simg[(y + ky) * 36 + q * 4];
#pragma unroll
        for (int kx = 0; kx < 9; ++kx) {
          const float w = wr[ky * 9 + kx];
#pragma unroll
          for (int ox = 0; ox < 20; ++ox) a20[ox] = fmaf(w, rr[ox + kx], a20[ox]);
        }
      }
      short* hp = &c1hi[(y * 20) * 40 + ci];
      short* lp = &c1lo[(y * 20) * 40 + ci];
#pragma unroll
      for (int x = 0; x < 20; ++x) {
        const float v = fmaxf(a20[x], 0.f);
        const short hi = f2bf(v);
        hp[x * 40] = hi;
        lp[x * 40] = f2bf(v - bf2f(hi));
      }
    }
    __syncthreads();
    // ---- phase B: 81 taps, K=32, 3-product split MFMA ----
    for (int ky = 0; ky < 9; ++ky) {
#pragma unroll
      for (int kx = 0; kx < 9; ++kx) {
        const int rowoff = (ky * 20 + kx) * 40;
        s16x8 ah[3], al[3];
#pragma unroll
        for (int m = 0; m < 3; ++m) {
          const int ix = base0[m] + rowoff;
          ah[m] = *(const s16x8*)&c1hi[ix];  // one b128 each
          al[m] = *(const s16x8*)&c1lo[ix];
        }
        const size_t tbase = (size_t)(ky * 9 + kx) * 65536 + chunk * 32;
        s16x8 bh[2], bl[2];
#pragma unroll
        for (int j = 0; j < 2; ++j) {
          bh[j] = *(const s16x8*)&whi[tbase + boff[j]];
          bl[j] = *(const s16x8*)&wlo[tbase + boff[j]];
        }
#pragma unroll
        for (int m = 0; m < 3; ++m)
#pragma unroll
          for (int j = 0; j < 2; ++j)
            acc[m][j] = __builtin_amdgcn_mfma_f32_16x16x32_bf16(ah[m], bh[j], acc[m][j], 0, 0, 0);
#pragma unroll
        for (int m = 0; m < 3; ++m)
#pragma unroll
          for (int j = 0; j < 2; ++j)
            acc[m][j] = __builtin_amdgcn_mfma_f32_16x16x32_bf16(al[m], bh[j], acc[m][j], 0, 0, 0);
#pragma unroll
        for (int m = 0; m < 3; ++m)
#pragma unroll
          for (int j = 0; j < 2; ++j)
            acc[m][j] = __builtin_amdgcn_mfma_f32_16x16x32_bf16(ah[m], bl[j], acc[m][j], 0, 0, 0);
      }
    }
  }
  // ---- store: D col=lane&15, row=(lane>>4)*4+reg; xcaps[b][n][d] ----
#pragma unroll
  for (int m = 0; m < 3; ++m) {
#pragma unroll
    for (int jj = 0; jj < 4; ++jj) {
      const int pos = m * 16 + kg * 4 + jj;
      if (pos < 36) {
#pragma unroll
        for (int j = 0; j < 2; ++j) {
          const int co = con[j];
          const int n = (co & 31) * 36 + pos;
          xcaps[((size_t)b * 1152 + n) * 8 + (co >> 5)] = acc[m][j][jj] + bias[j];
        }
      }
    }
  }
}

// ---------------- fused u_hat + routing: block per (o,b) ----------------
__global__ __launch_bounds__(256) void routing_fused(const float* __restrict__ xcaps,
                                                     const float* __restrict__ W,
                                                     float* __restrict__ out) {
  const int o = blockIdx.x >> 8;
  const int b = blockIdx.x & 255;
  const int t = threadIdx.x;
  const int k = t & 15, ng = t >> 4;
  __shared__ float xs[1152 * 9];  // x[b] padded stride 8->9
  __shared__ double redA[256];
  __shared__ double redB[256];
  __shared__ float s_s[16];
  __shared__ float s_sv;
  __shared__ double s_f;

  {
    const float4* src = (const float4*)(xcaps + (size_t)b * 9216);
    for (int idx = t; idx < 2304; idx += 256) {
      float4 v = src[idx];
      const int n = idx >> 1, h = idx & 1;
      float* dst = &xs[n * 9 + h * 4];
      dst[0] = v.x; dst[1] = v.y; dst[2] = v.z; dst[3] = v.w;
    }
  }
  __syncthreads();

  const int n0 = ng * 72;
  float u[72];
  const float* wp = W + ((size_t)(n0 * 10 + o) * 16 + k) * 8;
#pragma unroll
  for (int i = 0; i < 72; ++i) {
    const float* wq = wp + (size_t)i * 1280;
    const float4 wa = *(const float4*)wq;
    const float4 wb = *(const float4*)(wq + 4);
    const float* xp = &xs[(n0 + i) * 9];
    float s = fmaf(wa.x, xp[0], 0.f);
    s = fmaf(wa.y, xp[1], s);
    s = fmaf(wa.z, xp[2], s);
    s = fmaf(wa.w, xp[3], s);
    s = fmaf(wb.x, xp[4], s);
    s = fmaf(wb.y, xp[5], s);
    s = fmaf(wb.z, xp[6], s);
    s = fmaf(wb.w, xp[7], s);
    u[i] = s;
  }

  // ---- pass 1: uniform c = 1/1152 ----
  double S = 0.0;
#pragma unroll
  for (int i = 0; i < 72; ++i) S += (double)u[i];
  redA[t] = S;
  __syncthreads();
  if (t < 16) {
    double tt = 0.0;
#pragma unroll
    for (int g = 0; g < 16; ++g) tt += redA[g * 16 + t];
    s_s[t] = (float)(tt * (double)(1.0f / 1152.0f));
  }
  __syncthreads();
  if (t == 0) {
    double sn = 0.0;
#pragma unroll
    for (int kk = 0; kk < 16; ++kk) sn += (double)s_s[kk] * (double)s_s[kk];
    const double f = sn / ((1.0 + sn) * sqrt(sn));
    double sv = 0.0;
#pragma unroll
    for (int kk = 0; kk < 16; ++kk) sv += (double)s_s[kk] * f;
    s_sv = (float)sv;
  }
  __syncthreads();
  const float sv1 = s_sv;

  // ---- pass 2: logits u*sv1 ----
  double E = 0.0, EU = 0.0;
#pragma unroll
  for (int i = 0; i < 72; ++i) {
    const float e = expf(u[i] * sv1);
    E += (double)e;
    EU += (double)e * (double)u[i];
  }
  redA[t] = E; redB[t] = EU;
  __syncthreads();
  if (t < 16) {
    double te = 0.0, tu = 0.0;
#pragma unroll
    for (int g = 0; g < 16; ++g) { te += redA[g * 16 + t]; tu += redB[g * 16 + t]; }
    s_s[t] = (float)(tu / te);
  }
  __syncthreads();
  if (t == 0) {
    double sn = 0.0;
#pragma unroll
    for (int kk = 0; kk < 16; ++kk) sn += (double)s_s[kk] * (double)s_s[kk];
    const double f = sn / ((1.0 + sn) * sqrt(sn));
    double sv = 0.0;
#pragma unroll
    for (int kk = 0; kk < 16; ++kk) sv += (double)s_s[kk] * f;
    s_sv = sv1 + (float)sv;
  }
  __syncthreads();
  const float sv12 = s_sv;

  // ---- pass 3 -> output ----
  E = 0.0; EU = 0.0;
#pragma unroll
  for (int i = 0; i < 72; ++i) {
    const float e = expf(u[i] * sv12);
    E += (double)e;
    EU += (double)e * (double)u[i];
  }
  redA[t] = E; redB[t] = EU;
  __syncthreads();
  if (t < 16) {
    double te = 0.0, tu = 0.0;
#pragma unroll
    for (int g = 0; g < 16; ++g) { te += redA[g * 16 + t]; tu += redB[g * 16 + t]; }
    s_s[t] = (float)(tu / te);
  }
  __syncthreads();
  if (t == 0) {
    double sn = 0.0;
#pragma unroll
    for (int kk = 0; kk < 16; ++kk) sn += (double)s_s[kk] * (double)s_s[kk];
    s_f = sn / ((1.0 + sn) * sqrt(sn));
  }
  __syncthreads();
  if (t < 16) out[b * 160 + o * 16 + t] = (float)((double)s_s[t] * s_f);
}

extern "C" void kernel_launch(void* const* d_in, const int* in_sizes, int n_in,
                              void* d_out, int out_size, void* d_ws, size_t ws_size,
                              hipStream_t stream) {
  const float* data = (const float*)d_in[0];
  const float* w1   = (const float*)d_in[1];
  const float* b1   = (const float*)d_in[2];
  const float* w2   = (const float*)d_in[3];
  const float* b2   = (const float*)d_in[4];
  const float* W    = (const float*)d_in[5];
  float* out = (float*)d_out;

  short* whi   = (short*)d_ws;            // 5,308,416 shorts
  short* wlo   = whi + 5308416;           // 5,308,416 shorts
  float* xcaps = (float*)(wlo + 5308416); // 2,359,296 floats

  prep_w2<<<256, 256, 0, stream>>>(w2, whi, wlo);
  conv2_mfma<<<512, 256, 0, stream>>>(data, w1, b1, whi, wlo, b2, xcaps);
  routing_fused<<<2560, 256, 0, stream>>>(xcaps, W, out);
}